// Round 9
// baseline (186.665 us; speedup 1.0000x reference)
//
#include <hip/hip_runtime.h>
#include <hip/hip_bf16.h>

#define NN 8192
#define DIM 128
#define KS 8            // split-K factor for PV
#define KSL (NN / KS)   // 1024 k per slice
#define RPB 64          // rows per SB block
#define KC 128          // k-chunk width in SB

typedef __attribute__((ext_vector_type(8))) short bf16x8;
typedef __attribute__((ext_vector_type(4))) float f32x4;
typedef __attribute__((ext_vector_type(4))) int i32x4;
typedef __attribute__((ext_vector_type(4))) unsigned int u32x4;
typedef __attribute__((ext_vector_type(4))) unsigned short u16x4;
typedef __attribute__((ext_vector_type(4))) short s16x4;

static __device__ inline unsigned short f2bf(float x) {
    __hip_bfloat16 b = __float2bfloat16(x);
    return *reinterpret_cast<unsigned short*>(&b);
}

struct BSplit { short hi, lo; };
static __device__ inline BSplit bsplit(float x) {
    BSplit r;
    __hip_bfloat16 h = __float2bfloat16(x);
    r.hi = *reinterpret_cast<short*>(&h);
    float rem = x - __bfloat162float(h);
    __hip_bfloat16 l = __float2bfloat16(rem);
    r.lo = *reinterpret_cast<short*>(&l);
    return r;
}

// ---------------------------------------------------------------------------
// K1M: Wh = h@W^T (split-bf16 MFMA, f32-grade), a1/a2 from the f32
// accumulators, packed tables pk[i] = {a2, bf16(E1)|bf16(E2)<<16}, and
// whbT (bf16, tiled [k>>3][dim][k&7]). grid 128 x 64 rows, 4 waves.
// ---------------------------------------------------------------------------
__global__ __launch_bounds__(256) void k1m(const float* __restrict__ h,
                                           const float* __restrict__ W,
                                           const float* __restrict__ a,
                                           __hip_bfloat16* __restrict__ whbT,
                                           float* __restrict__ a1g,
                                           float2* __restrict__ pk) {
    __shared__ short whi[128 * 132];         // W hi, row stride 132 (264B)
    __shared__ short wlo[128 * 132];         // W lo
    __shared__ short wt[8 * 128 * 8];        // whbT retile staging (16 KB)
    __shared__ float a_sh[256];

    const int tid = threadIdx.x;
    const int wv = tid >> 6, lane = tid & 63;
    const int r0 = blockIdx.x * 64;

    for (int idx = tid; idx < 128 * 128; idx += 256) {
        const int d = idx >> 7, k = idx & 127;
        BSplit s = bsplit(W[idx]);
        whi[d * 132 + k] = s.hi;
        wlo[d * 132 + k] = s.lo;
    }
    a_sh[tid] = a[tid];
    __syncthreads();

    f32x4 acc[8];
    #pragma unroll
    for (int n = 0; n < 8; ++n) acc[n] = (f32x4){0.f, 0.f, 0.f, 0.f};

    const int arow = r0 + wv * 16 + (lane & 15);
    const int ksub = (lane >> 4) * 8;
    const float* hp = h + (size_t)arow * DIM + ksub;

    #pragma unroll
    for (int kk = 0; kk < 128; kk += 32) {
        f32x4 x0 = *(const f32x4*)(hp + kk);
        f32x4 x1 = *(const f32x4*)(hp + kk + 4);
        bf16x8 ah, al;
        {
            BSplit s0 = bsplit(x0.x), s1 = bsplit(x0.y), s2 = bsplit(x0.z), s3 = bsplit(x0.w);
            BSplit s4 = bsplit(x1.x), s5 = bsplit(x1.y), s6 = bsplit(x1.z), s7 = bsplit(x1.w);
            ah[0] = s0.hi; al[0] = s0.lo; ah[1] = s1.hi; al[1] = s1.lo;
            ah[2] = s2.hi; al[2] = s2.lo; ah[3] = s3.hi; al[3] = s3.lo;
            ah[4] = s4.hi; al[4] = s4.lo; ah[5] = s5.hi; al[5] = s5.lo;
            ah[6] = s6.hi; al[6] = s6.lo; ah[7] = s7.hi; al[7] = s7.lo;
        }
        #pragma unroll
        for (int n = 0; n < 8; ++n) {
            const int boff = (n * 16 + (lane & 15)) * 132 + kk + ksub;
            bf16x8 bh = *(const bf16x8*)(whi + boff);
            bf16x8 bl = *(const bf16x8*)(wlo + boff);
            acc[n] = __builtin_amdgcn_mfma_f32_16x16x32_bf16(ah, bh, acc[n], 0, 0, 0);
            acc[n] = __builtin_amdgcn_mfma_f32_16x16x32_bf16(ah, bl, acc[n], 0, 0, 0);
            acc[n] = __builtin_amdgcn_mfma_f32_16x16x32_bf16(al, bh, acc[n], 0, 0, 0);
        }
    }

    float p1[4] = {0.f, 0.f, 0.f, 0.f}, p2[4] = {0.f, 0.f, 0.f, 0.f};
    #pragma unroll
    for (int n = 0; n < 8; ++n) {
        const float av1 = a_sh[n * 16 + (lane & 15)];
        const float av2 = a_sh[128 + n * 16 + (lane & 15)];
        #pragma unroll
        for (int q = 0; q < 4; ++q) {
            p1[q] += acc[n][q] * av1;
            p2[q] += acc[n][q] * av2;
        }
    }
    #pragma unroll
    for (int o = 8; o >= 1; o >>= 1) {
        #pragma unroll
        for (int q = 0; q < 4; ++q) {
            p1[q] += __shfl_xor(p1[q], o, 64);
            p2[q] += __shfl_xor(p2[q], o, 64);
        }
    }
    if ((lane & 15) == 0) {
        #pragma unroll
        for (int q = 0; q < 4; ++q) {
            const int row = r0 + wv * 16 + (lane >> 4) * 4 + q;
            a1g[row] = p1[q];
            const float E1v = expf(p2[q]);
            const float E2v = expf(0.2f * p2[q]);
            unsigned ub = (unsigned)f2bf(E1v) | ((unsigned)f2bf(E2v) << 16);
            float2 pv;
            pv.x = p2[q];
            pv.y = __uint_as_float(ub);
            pk[row] = pv;
        }
    }

    #pragma unroll
    for (int n = 0; n < 8; ++n) {
        #pragma unroll
        for (int q = 0; q < 4; ++q) {
            const int kloc = wv * 16 + (lane >> 4) * 4 + q;   // block-local k
            const int d = n * 16 + (lane & 15);
            wt[(kloc >> 3) * 1024 + d * 8 + (kloc & 7)] = (short)f2bf(acc[n][q]);
        }
    }
    __syncthreads();
    short* dst = reinterpret_cast<short*>(whbT) + ((size_t)r0 << 7);
    for (int idx = tid * 4; idx < 8192; idx += 1024)
        *(s16x4*)(dst + idx) = *(const s16x4*)(wt + idx);
}

// ---------------------------------------------------------------------------
// SA: stream adj (1 wave per row, i32x4 16B/lane NT loads): bitmask + row
// softmax sums from packed tables. Bit layout: col j -> word
// (j>>8)*8 + ((j>>7)&1)*4 + (j&3), bit (j>>2)&31.
// ---------------------------------------------------------------------------
__global__ __launch_bounds__(256, 8) void sa_scan(const int* __restrict__ adj,
                                                  const float* __restrict__ a1g,
                                                  const float2* __restrict__ pk,
                                                  unsigned* __restrict__ bm,
                                                  float* __restrict__ crow) {
    const int wid = threadIdx.x >> 6, lane = threadIdx.x & 63;
    const int i = blockIdx.x * 4 + wid;
    const float a1i = a1g[i];
    const int* arow = adj + (size_t)i * NN;
    unsigned* brow = bm + (size_t)i * (NN / 32);
    const float* pkf = reinterpret_cast<const float*>(pk);

    float s1 = 0.f, s2 = 0.f;
    #pragma unroll 2
    for (int it = 0; it < NN / 256; ++it) {
        const int j0 = it * 256 + lane * 4;
        i32x4 v = __builtin_nontemporal_load((const i32x4*)(arow + j0));
        unsigned long long m0 = __ballot(v.x != 0);
        unsigned long long m1 = __ballot(v.y != 0);
        unsigned long long m2 = __ballot(v.z != 0);
        unsigned long long m3 = __ballot(v.w != 0);
        if (lane == 0) {
            u32x4 w;
            w.x = (unsigned)m0; w.y = (unsigned)m1;
            w.z = (unsigned)m2; w.w = (unsigned)m3;
            *(u32x4*)(brow + it * 8) = w;
        } else if (lane == 32) {
            u32x4 w;
            w.x = (unsigned)(m0 >> 32); w.y = (unsigned)(m1 >> 32);
            w.z = (unsigned)(m2 >> 32); w.w = (unsigned)(m3 >> 32);
            *(u32x4*)(brow + it * 8 + 4) = w;
        }
        f32x4 pa = *(const f32x4*)(pkf + 2 * j0);
        f32x4 pb = *(const f32x4*)(pkf + 2 * j0 + 4);
        float x2, e1, e2; unsigned ub; bool px;

        x2 = pa.x; ub = __float_as_uint(pa.y);
        e1 = __uint_as_float(ub << 16); e2 = __uint_as_float(ub & 0xffff0000u);
        px = (a1i + x2 >= 0.f);
        s1 += (v.x && px) ? e1 : 0.f;  s2 += (v.x && !px) ? e2 : 0.f;

        x2 = pa.z; ub = __float_as_uint(pa.w);
        e1 = __uint_as_float(ub << 16); e2 = __uint_as_float(ub & 0xffff0000u);
        px = (a1i + x2 >= 0.f);
        s1 += (v.y && px) ? e1 : 0.f;  s2 += (v.y && !px) ? e2 : 0.f;

        x2 = pb.x; ub = __float_as_uint(pb.y);
        e1 = __uint_as_float(ub << 16); e2 = __uint_as_float(ub & 0xffff0000u);
        px = (a1i + x2 >= 0.f);
        s1 += (v.z && px) ? e1 : 0.f;  s2 += (v.z && !px) ? e2 : 0.f;

        x2 = pb.z; ub = __float_as_uint(pb.w);
        e1 = __uint_as_float(ub << 16); e2 = __uint_as_float(ub & 0xffff0000u);
        px = (a1i + x2 >= 0.f);
        s1 += (v.w && px) ? e1 : 0.f;  s2 += (v.w && !px) ? e2 : 0.f;
    }
    #pragma unroll
    for (int o = 32; o >= 1; o >>= 1) {
        s1 += __shfl_xor(s1, o, 64);
        s2 += __shfl_xor(s2, o, 64);
    }
    if (lane == 0) {
        float c1 = 0.f, c2 = 0.f;
        if (s1 + s2 > 0.f) {
            float e1v = expf(a1i);
            float e2v = expf(0.2f * a1i);
            float S = e1v * s1 + e2v * s2;
            c1 = e1v / S;
            c2 = e2v / S;
        }
        crow[i * 4 + 0] = c1;
        crow[i * 4 + 1] = c2;
        crow[i * 4 + 2] = a1i;
        crow[i * 4 + 3] = 0.f;
    }
}

// ---------------------------------------------------------------------------
// SB: fused alpha-write + PV MFMA, split-K. grid (NN/64, KS=8), 512 threads.
// Pipeline upgrades vs r8: (1) raw lgkmcnt(0)+s_barrier per chunk (no vmcnt
// drain: NT alpha stores + pk prefetches stay in flight across barriers);
// (2) pk register-prefetch one chunk ahead (hidden under barrier + MFMA);
// (3) setprio(1) around the MFMA cluster.
// dbuf WAR safety: one barrier/chunk still separates every read of buffer b
// from its next overwrite (writes to b at t+2 are after barrier t+1, which
// all waves reach only after their MFMA reads of b at t).
// ---------------------------------------------------------------------------
__global__ __launch_bounds__(512, 6) void sb_pv(const unsigned* __restrict__ bm,
                                                const float* __restrict__ crowG,
                                                const float2* __restrict__ pk,
                                                const __hip_bfloat16* __restrict__ whbT,
                                                float* __restrict__ alpha,
                                                float* __restrict__ part) {
    __shared__ unsigned bmL[RPB][KSL / 32];              // 8 KB
    __shared__ __hip_bfloat16 abuf[2][RPB][KC + 8];      // 34.8 KB
    __shared__ float crowL[RPB][4];                      // 1 KB

    const int tid = threadIdx.x;
    const int wv = tid >> 6, lane = tid & 63;
    const int r0 = blockIdx.x * RPB;
    const int ks = blockIdx.y;
    const int k0 = ks * KSL;
    const float* pkf = reinterpret_cast<const float*>(pk);

    {   // preload bitmask slice + row coefficients
        const int r = tid >> 3, wq = (tid & 7) << 2;     // 64 rows x 8 quads
        *(u32x4*)(&bmL[r][wq]) =
            *(const u32x4*)(bm + (size_t)(r0 + r) * (NN / 32) + ks * (KSL / 32) + wq);
        if (tid < RPB * 4)
            crowL[tid >> 2][tid & 3] = crowG[(r0 + (tid >> 2)) * 4 + (tid & 3)];
    }
    __syncthreads();

    f32x4 acc[4];
    #pragma unroll
    for (int rt = 0; rt < 4; ++rt) acc[rt] = (f32x4){0.f, 0.f, 0.f, 0.f};
    const int n0 = wv * 16;
    const short* wb = reinterpret_cast<const short*>(whbT);
    const short* bbase = wb + (size_t)(n0 + (lane & 15)) * 8 + (size_t)(lane >> 4) * 1024;

    // prefetch pk for chunk 0
    f32x4 pf0_0, pf1_0, pf0_1, pf1_1, pf0_2, pf1_2, pf0_3, pf1_3;
    {
        const int j = k0 + ((tid & 31) << 2);
        pf0_0 = *(const f32x4*)(pkf + 2 * (j + 0 * 128));   // v rows share cols? no:
        pf1_0 = *(const f32x4*)(pkf + 2 * (j + 0 * 128) + 4);
        pf0_1 = *(const f32x4*)(pkf + 2 * (j + 0 * 128));
        pf1_1 = *(const f32x4*)(pkf + 2 * (j + 0 * 128) + 4);
        pf0_2 = pf0_1; pf1_2 = pf1_1; pf0_3 = pf0_1; pf1_3 = pf1_1;
        // NOTE: cols depend only on (vid & 31), and vid = v*512+tid keeps
        // (vid & 31) == (tid & 31) for all v — all 4 v-iters read the SAME
        // 16 cols for different rows. One prefetch pair serves all 4.
    }

    for (int kc = 0; kc < KSL; kc += KC) {
        const int dbuf = (kc >> 7) & 1;
        // ---- write phase: alpha for 64 rows x 128 cols (this chunk) ----
        #pragma unroll
        for (int v = 0; v < 4; ++v) {
            const int vid = v * 512 + tid;
            const int r = vid >> 5;                      // 32 threads per row
            const int c4 = (vid & 31) << 2;
            const int jl = kc + c4;                      // col within slice
            const int j = k0 + jl;                       // global col
            const int wbw = ((jl >> 8) << 3) + (((jl >> 7) & 1) << 2);
            i32x4 w4 = *(const i32x4*)(&bmL[r][wbw]);
            const unsigned p = (jl >> 2) & 31;
            const float c1 = crowL[r][0], c2 = crowL[r][1], a1i = crowL[r][2];
            const f32x4 pa = pf0_0;                      // same cols for all v
            const f32x4 pb = pf1_0;
            f32x4 al;
            {
                unsigned ub = __float_as_uint(pa.y);
                float e1 = __uint_as_float(ub << 16), e2 = __uint_as_float(ub & 0xffff0000u);
                al.x = ((w4.x >> p) & 1) ? ((a1i + pa.x >= 0.f) ? c1 * e1 : c2 * e2) : 0.f;
            }
            {
                unsigned ub = __float_as_uint(pa.w);
                float e1 = __uint_as_float(ub << 16), e2 = __uint_as_float(ub & 0xffff0000u);
                al.y = ((w4.y >> p) & 1) ? ((a1i + pa.z >= 0.f) ? c1 * e1 : c2 * e2) : 0.f;
            }
            {
                unsigned ub = __float_as_uint(pb.y);
                float e1 = __uint_as_float(ub << 16), e2 = __uint_as_float(ub & 0xffff0000u);
                al.z = ((w4.z >> p) & 1) ? ((a1i + pb.x >= 0.f) ? c1 * e1 : c2 * e2) : 0.f;
            }
            {
                unsigned ub = __float_as_uint(pb.w);
                float e1 = __uint_as_float(ub << 16), e2 = __uint_as_float(ub & 0xffff0000u);
                al.w = ((w4.w >> p) & 1) ? ((a1i + pb.z >= 0.f) ? c1 * e1 : c2 * e2) : 0.f;
            }
            __builtin_nontemporal_store(al, (f32x4*)(alpha + (size_t)(r0 + r) * NN + j));
            u16x4 ub4;
            ub4.x = f2bf(al.x); ub4.y = f2bf(al.y); ub4.z = f2bf(al.z); ub4.w = f2bf(al.w);
            *(u16x4*)(&abuf[dbuf][r][c4]) = ub4;
        }
        // ---- issue next chunk's pk prefetch (in flight across barrier) ----
        if (kc + KC < KSL) {
            const int jn = k0 + kc + KC + ((tid & 31) << 2);
            pf0_0 = *(const f32x4*)(pkf + 2 * jn);
            pf1_0 = *(const f32x4*)(pkf + 2 * jn + 4);
        }
        // ---- raw barrier: LDS visibility only, no vmcnt drain ----
        asm volatile("s_waitcnt lgkmcnt(0)" ::: "memory");
        __builtin_amdgcn_s_barrier();
        // ---- MFMA phase ----
        __builtin_amdgcn_s_setprio(1);
        #pragma unroll
        for (int kk = 0; kk < KC; kk += 32) {
            bf16x8 bf = *(const bf16x8*)(bbase + (size_t)((k0 + kc + kk) >> 3) * 1024);
            #pragma unroll
            for (int rt = 0; rt < 4; ++rt) {
                bf16x8 af = *(const bf16x8*)(&abuf[dbuf][rt * 16 + (lane & 15)][kk + 8 * (lane >> 4)]);
                acc[rt] = __builtin_amdgcn_mfma_f32_16x16x32_bf16(af, bf, acc[rt], 0, 0, 0);
            }
        }
        __builtin_amdgcn_s_setprio(0);
    }

    float* pb2 = part + (size_t)ks * NN * DIM;
    const int rb = (lane >> 4) * 4;
    #pragma unroll
    for (int rt = 0; rt < 4; ++rt) {
        #pragma unroll
        for (int q = 0; q < 4; ++q)
            __builtin_nontemporal_store(acc[rt][q],
                pb2 + (size_t)(r0 + rt * 16 + rb + q) * DIM + n0 + (lane & 15));
    }
}

// ---------------------------------------------------------------------------
// K5: reduce split-K partials -> out (vectorized, NT reads)
// ---------------------------------------------------------------------------
__global__ __launch_bounds__(256) void k5_reduce(const float* __restrict__ part,
                                                 float* __restrict__ out) {
    const size_t idx = ((size_t)blockIdx.x * 256 + threadIdx.x) * 4;
    f32x4 s = (f32x4){0.f, 0.f, 0.f, 0.f};
    #pragma unroll
    for (int ks = 0; ks < KS; ++ks)
        s += __builtin_nontemporal_load((const f32x4*)(part + (size_t)ks * NN * DIM + idx));
    *(f32x4*)(out + idx) = s;
}

// ---------------------------------------------------------------------------
extern "C" void kernel_launch(void* const* d_in, const int* in_sizes, int n_in,
                              void* d_out, int out_size, void* d_ws, size_t ws_size,
                              hipStream_t stream) {
    const float* h   = (const float*)d_in[0];
    const int*   adj = (const int*)d_in[1];
    const float* W   = (const float*)d_in[2];
    const float* a   = (const float*)d_in[3];

    float* out   = (float*)d_out;
    float* alpha = out + (size_t)NN * DIM;

    char* ws = (char*)d_ws;
    __hip_bfloat16* whbT = (__hip_bfloat16*)(ws);          // 2 MB
    float* a1g   = (float*)(ws + 0x200000);                // 32 KB
    float2* pk   = (float2*)(ws + 0x208000);               // 64 KB
    float* crow  = (float*)(ws + 0x218000);                // 128 KB
    unsigned* bm = (unsigned*)(ws + 0x240000);             // 8 MB
    float* part  = (float*)(ws + 0xA40000);                // KS*4 MB = 32 MB

    k1m<<<NN / 64, 256, 0, stream>>>(h, W, a, whbT, a1g, pk);
    sa_scan<<<NN / 4, 256, 0, stream>>>(adj, a1g, pk, bm, crow);
    sb_pv<<<dim3(NN / RPB, KS), 512, 0, stream>>>(bm, crow, pk, whbT, alpha, part);
    k5_reduce<<<NN * DIM / 1024, 256, 0, stream>>>(part, out);
}

// Round 10
// 168.081 us; speedup vs baseline: 1.1106x; 1.1106x over previous
//
#include <hip/hip_runtime.h>
#include <hip/hip_bf16.h>

#define NN 8192
#define DIM 128
#define KS 8            // split-K factor for PV
#define KSL (NN / KS)   // 1024 k per slice
#define RPB 64          // rows per SB block
#define KC 128          // k-chunk width in SB

typedef __attribute__((ext_vector_type(8))) short bf16x8;
typedef __attribute__((ext_vector_type(4))) float f32x4;
typedef __attribute__((ext_vector_type(4))) int i32x4;
typedef __attribute__((ext_vector_type(4))) unsigned int u32x4;
typedef __attribute__((ext_vector_type(4))) unsigned short u16x4;
typedef __attribute__((ext_vector_type(4))) short s16x4;

static __device__ inline unsigned short f2bf(float x) {
    __hip_bfloat16 b = __float2bfloat16(x);
    return *reinterpret_cast<unsigned short*>(&b);
}

struct BSplit { short hi, lo; };
static __device__ inline BSplit bsplit(float x) {
    BSplit r;
    __hip_bfloat16 h = __float2bfloat16(x);
    r.hi = *reinterpret_cast<short*>(&h);
    float rem = x - __bfloat162float(h);
    __hip_bfloat16 l = __float2bfloat16(rem);
    r.lo = *reinterpret_cast<short*>(&l);
    return r;
}

// ---------------------------------------------------------------------------
// K1M: Wh = h@W^T (split-bf16 MFMA, f32-grade), a1/a2 from the f32
// accumulators, packed tables pk[i] = {a2, bf16(E1)|bf16(E2)<<16}, and
// whbT (bf16, tiled [k>>3][dim][k&7]). grid 128 x 64 rows, 4 waves.
// ---------------------------------------------------------------------------
__global__ __launch_bounds__(256) void k1m(const float* __restrict__ h,
                                           const float* __restrict__ W,
                                           const float* __restrict__ a,
                                           __hip_bfloat16* __restrict__ whbT,
                                           float* __restrict__ a1g,
                                           float2* __restrict__ pk) {
    __shared__ short whi[128 * 132];         // W hi, row stride 132 (264B)
    __shared__ short wlo[128 * 132];         // W lo
    __shared__ short wt[8 * 128 * 8];        // whbT retile staging (16 KB)
    __shared__ float a_sh[256];

    const int tid = threadIdx.x;
    const int wv = tid >> 6, lane = tid & 63;
    const int r0 = blockIdx.x * 64;

    for (int idx = tid; idx < 128 * 128; idx += 256) {
        const int d = idx >> 7, k = idx & 127;
        BSplit s = bsplit(W[idx]);
        whi[d * 132 + k] = s.hi;
        wlo[d * 132 + k] = s.lo;
    }
    a_sh[tid] = a[tid];
    __syncthreads();

    f32x4 acc[8];
    #pragma unroll
    for (int n = 0; n < 8; ++n) acc[n] = (f32x4){0.f, 0.f, 0.f, 0.f};

    const int arow = r0 + wv * 16 + (lane & 15);
    const int ksub = (lane >> 4) * 8;
    const float* hp = h + (size_t)arow * DIM + ksub;

    #pragma unroll
    for (int kk = 0; kk < 128; kk += 32) {
        f32x4 x0 = *(const f32x4*)(hp + kk);
        f32x4 x1 = *(const f32x4*)(hp + kk + 4);
        bf16x8 ah, al;
        {
            BSplit s0 = bsplit(x0.x), s1 = bsplit(x0.y), s2 = bsplit(x0.z), s3 = bsplit(x0.w);
            BSplit s4 = bsplit(x1.x), s5 = bsplit(x1.y), s6 = bsplit(x1.z), s7 = bsplit(x1.w);
            ah[0] = s0.hi; al[0] = s0.lo; ah[1] = s1.hi; al[1] = s1.lo;
            ah[2] = s2.hi; al[2] = s2.lo; ah[3] = s3.hi; al[3] = s3.lo;
            ah[4] = s4.hi; al[4] = s4.lo; ah[5] = s5.hi; al[5] = s5.lo;
            ah[6] = s6.hi; al[6] = s6.lo; ah[7] = s7.hi; al[7] = s7.lo;
        }
        #pragma unroll
        for (int n = 0; n < 8; ++n) {
            const int boff = (n * 16 + (lane & 15)) * 132 + kk + ksub;
            bf16x8 bh = *(const bf16x8*)(whi + boff);
            bf16x8 bl = *(const bf16x8*)(wlo + boff);
            acc[n] = __builtin_amdgcn_mfma_f32_16x16x32_bf16(ah, bh, acc[n], 0, 0, 0);
            acc[n] = __builtin_amdgcn_mfma_f32_16x16x32_bf16(ah, bl, acc[n], 0, 0, 0);
            acc[n] = __builtin_amdgcn_mfma_f32_16x16x32_bf16(al, bh, acc[n], 0, 0, 0);
        }
    }

    float p1[4] = {0.f, 0.f, 0.f, 0.f}, p2[4] = {0.f, 0.f, 0.f, 0.f};
    #pragma unroll
    for (int n = 0; n < 8; ++n) {
        const float av1 = a_sh[n * 16 + (lane & 15)];
        const float av2 = a_sh[128 + n * 16 + (lane & 15)];
        #pragma unroll
        for (int q = 0; q < 4; ++q) {
            p1[q] += acc[n][q] * av1;
            p2[q] += acc[n][q] * av2;
        }
    }
    #pragma unroll
    for (int o = 8; o >= 1; o >>= 1) {
        #pragma unroll
        for (int q = 0; q < 4; ++q) {
            p1[q] += __shfl_xor(p1[q], o, 64);
            p2[q] += __shfl_xor(p2[q], o, 64);
        }
    }
    if ((lane & 15) == 0) {
        #pragma unroll
        for (int q = 0; q < 4; ++q) {
            const int row = r0 + wv * 16 + (lane >> 4) * 4 + q;
            a1g[row] = p1[q];
            const float E1v = expf(p2[q]);
            const float E2v = expf(0.2f * p2[q]);
            unsigned ub = (unsigned)f2bf(E1v) | ((unsigned)f2bf(E2v) << 16);
            float2 pv;
            pv.x = p2[q];
            pv.y = __uint_as_float(ub);
            pk[row] = pv;
        }
    }

    #pragma unroll
    for (int n = 0; n < 8; ++n) {
        #pragma unroll
        for (int q = 0; q < 4; ++q) {
            const int kloc = wv * 16 + (lane >> 4) * 4 + q;   // block-local k
            const int d = n * 16 + (lane & 15);
            wt[(kloc >> 3) * 1024 + d * 8 + (kloc & 7)] = (short)f2bf(acc[n][q]);
        }
    }
    __syncthreads();
    short* dst = reinterpret_cast<short*>(whbT) + ((size_t)r0 << 7);
    for (int idx = tid * 4; idx < 8192; idx += 1024)
        *(s16x4*)(dst + idx) = *(const s16x4*)(wt + idx);
}

// ---------------------------------------------------------------------------
// SA: stream adj (1 wave per row, i32x4 16B/lane NT loads): bitmask + row
// softmax sums from packed tables. Bit layout: col j -> word
// (j>>8)*8 + ((j>>7)&1)*4 + (j&3), bit (j>>2)&31.
// ---------------------------------------------------------------------------
__global__ __launch_bounds__(256, 8) void sa_scan(const int* __restrict__ adj,
                                                  const float* __restrict__ a1g,
                                                  const float2* __restrict__ pk,
                                                  unsigned* __restrict__ bm,
                                                  float* __restrict__ crow) {
    const int wid = threadIdx.x >> 6, lane = threadIdx.x & 63;
    const int i = blockIdx.x * 4 + wid;
    const float a1i = a1g[i];
    const int* arow = adj + (size_t)i * NN;
    unsigned* brow = bm + (size_t)i * (NN / 32);
    const float* pkf = reinterpret_cast<const float*>(pk);

    float s1 = 0.f, s2 = 0.f;
    #pragma unroll 2
    for (int it = 0; it < NN / 256; ++it) {
        const int j0 = it * 256 + lane * 4;
        i32x4 v = __builtin_nontemporal_load((const i32x4*)(arow + j0));
        unsigned long long m0 = __ballot(v.x != 0);
        unsigned long long m1 = __ballot(v.y != 0);
        unsigned long long m2 = __ballot(v.z != 0);
        unsigned long long m3 = __ballot(v.w != 0);
        if (lane == 0) {
            u32x4 w;
            w.x = (unsigned)m0; w.y = (unsigned)m1;
            w.z = (unsigned)m2; w.w = (unsigned)m3;
            *(u32x4*)(brow + it * 8) = w;
        } else if (lane == 32) {
            u32x4 w;
            w.x = (unsigned)(m0 >> 32); w.y = (unsigned)(m1 >> 32);
            w.z = (unsigned)(m2 >> 32); w.w = (unsigned)(m3 >> 32);
            *(u32x4*)(brow + it * 8 + 4) = w;
        }
        f32x4 pa = *(const f32x4*)(pkf + 2 * j0);
        f32x4 pb = *(const f32x4*)(pkf + 2 * j0 + 4);
        float x2, e1, e2; unsigned ub; bool px;

        x2 = pa.x; ub = __float_as_uint(pa.y);
        e1 = __uint_as_float(ub << 16); e2 = __uint_as_float(ub & 0xffff0000u);
        px = (a1i + x2 >= 0.f);
        s1 += (v.x && px) ? e1 : 0.f;  s2 += (v.x && !px) ? e2 : 0.f;

        x2 = pa.z; ub = __float_as_uint(pa.w);
        e1 = __uint_as_float(ub << 16); e2 = __uint_as_float(ub & 0xffff0000u);
        px = (a1i + x2 >= 0.f);
        s1 += (v.y && px) ? e1 : 0.f;  s2 += (v.y && !px) ? e2 : 0.f;

        x2 = pb.x; ub = __float_as_uint(pb.y);
        e1 = __uint_as_float(ub << 16); e2 = __uint_as_float(ub & 0xffff0000u);
        px = (a1i + x2 >= 0.f);
        s1 += (v.z && px) ? e1 : 0.f;  s2 += (v.z && !px) ? e2 : 0.f;

        x2 = pb.z; ub = __float_as_uint(pb.w);
        e1 = __uint_as_float(ub << 16); e2 = __uint_as_float(ub & 0xffff0000u);
        px = (a1i + x2 >= 0.f);
        s1 += (v.w && px) ? e1 : 0.f;  s2 += (v.w && !px) ? e2 : 0.f;
    }
    #pragma unroll
    for (int o = 32; o >= 1; o >>= 1) {
        s1 += __shfl_xor(s1, o, 64);
        s2 += __shfl_xor(s2, o, 64);
    }
    if (lane == 0) {
        float c1 = 0.f, c2 = 0.f;
        if (s1 + s2 > 0.f) {
            float e1v = expf(a1i);
            float e2v = expf(0.2f * a1i);
            float S = e1v * s1 + e2v * s2;
            c1 = e1v / S;
            c2 = e2v / S;
        }
        crow[i * 4 + 0] = c1;
        crow[i * 4 + 1] = c2;
        crow[i * 4 + 2] = a1i;
        crow[i * 4 + 3] = 0.f;
    }
}

// ---------------------------------------------------------------------------
// SB: fused alpha-write + PV MFMA, split-K. grid (NN/64, KS=8), 512 threads.
// vs r8: bmL/crowL removed (bm quad is an L2 broadcast line shared by all 32
// threads of a row-chunk; crow lives in 12 regs), pa/pb hoisted to 1 load per
// chunk, LDS = abuf only (34.8 KB) -> 4 blocks/CU at <=64 VGPR
// (__launch_bounds__(512,8)). part stores non-NT (k5 reads it from L2).
// dbuf WAR: one barrier/chunk separates MFMA reads of buffer b from its
// next overwrite two chunks later.
// ---------------------------------------------------------------------------
__global__ __launch_bounds__(512, 8) void sb_pv(const unsigned* __restrict__ bm,
                                                const float* __restrict__ crowG,
                                                const float2* __restrict__ pk,
                                                const __hip_bfloat16* __restrict__ whbT,
                                                float* __restrict__ alpha,
                                                float* __restrict__ part) {
    __shared__ __hip_bfloat16 abuf[2][RPB][KC + 8];      // 34.8 KB (sole LDS)

    const int tid = threadIdx.x;
    const int wv = tid >> 6, lane = tid & 63;
    const int r0 = blockIdx.x * RPB;
    const int ks = blockIdx.y;
    const int k0 = ks * KSL;
    const float* pkf = reinterpret_cast<const float*>(pk);

    // this thread's 4 write-phase rows: r = rloc + 16*v
    const int rloc = tid >> 5;
    float c1r[4], c2r[4], a1r[4];
    #pragma unroll
    for (int v = 0; v < 4; ++v) {
        f32x4 cw = *(const f32x4*)(crowG + (size_t)(r0 + rloc + 16 * v) * 4);
        c1r[v] = cw.x; c2r[v] = cw.y; a1r[v] = cw.z;
    }

    f32x4 acc[4];
    #pragma unroll
    for (int rt = 0; rt < 4; ++rt) acc[rt] = (f32x4){0.f, 0.f, 0.f, 0.f};
    const int n0 = wv * 16;
    const short* wb = reinterpret_cast<const short*>(whbT);
    const short* bbase = wb + (size_t)(n0 + (lane & 15)) * 8 + (size_t)(lane >> 4) * 1024;

    const int cgrp = (tid & 31) << 2;        // col group (same every chunk)
    const unsigned pbit = tid & 31;          // = (jl>>2)&31 for all chunks

    for (int kc = 0; kc < KSL; kc += KC) {
        const int dbuf = (kc >> 7) & 1;
        const int jl = kc + cgrp;            // col within slice
        const int j = k0 + jl;               // global col
        const int wbw = ((jl >> 8) << 3) + (((jl >> 7) & 1) << 2);
        f32x4 pa = *(const f32x4*)(pkf + 2 * j);
        f32x4 pb = *(const f32x4*)(pkf + 2 * j + 4);
        #pragma unroll
        for (int v = 0; v < 4; ++v) {
            const int r = rloc + 16 * v;
            const int gr = r0 + r;
            u32x4 w4 = *(const u32x4*)(bm + (size_t)gr * (NN / 32) + ks * (KSL / 32) + wbw);
            const float c1 = c1r[v], c2 = c2r[v], a1i = a1r[v];
            f32x4 al;
            {
                unsigned ub = __float_as_uint(pa.y);
                float e1 = __uint_as_float(ub << 16), e2 = __uint_as_float(ub & 0xffff0000u);
                al.x = ((w4.x >> pbit) & 1) ? ((a1i + pa.x >= 0.f) ? c1 * e1 : c2 * e2) : 0.f;
            }
            {
                unsigned ub = __float_as_uint(pa.w);
                float e1 = __uint_as_float(ub << 16), e2 = __uint_as_float(ub & 0xffff0000u);
                al.y = ((w4.y >> pbit) & 1) ? ((a1i + pa.z >= 0.f) ? c1 * e1 : c2 * e2) : 0.f;
            }
            {
                unsigned ub = __float_as_uint(pb.y);
                float e1 = __uint_as_float(ub << 16), e2 = __uint_as_float(ub & 0xffff0000u);
                al.z = ((w4.z >> pbit) & 1) ? ((a1i + pb.x >= 0.f) ? c1 * e1 : c2 * e2) : 0.f;
            }
            {
                unsigned ub = __float_as_uint(pb.w);
                float e1 = __uint_as_float(ub << 16), e2 = __uint_as_float(ub & 0xffff0000u);
                al.w = ((w4.w >> pbit) & 1) ? ((a1i + pb.z >= 0.f) ? c1 * e1 : c2 * e2) : 0.f;
            }
            __builtin_nontemporal_store(al, (f32x4*)(alpha + (size_t)gr * NN + j));
            u16x4 ub4;
            ub4.x = f2bf(al.x); ub4.y = f2bf(al.y); ub4.z = f2bf(al.z); ub4.w = f2bf(al.w);
            *(u16x4*)(&abuf[dbuf][r][cgrp]) = ub4;
        }
        __syncthreads();
        #pragma unroll
        for (int kk = 0; kk < KC; kk += 32) {
            bf16x8 bf = *(const bf16x8*)(bbase + (size_t)((k0 + kc + kk) >> 3) * 1024);
            #pragma unroll
            for (int rt = 0; rt < 4; ++rt) {
                bf16x8 af = *(const bf16x8*)(&abuf[dbuf][rt * 16 + (lane & 15)][kk + 8 * (lane >> 4)]);
                acc[rt] = __builtin_amdgcn_mfma_f32_16x16x32_bf16(af, bf, acc[rt], 0, 0, 0);
            }
        }
    }

    float* pb2 = part + (size_t)ks * NN * DIM;
    const int rb = (lane >> 4) * 4;
    #pragma unroll
    for (int rt = 0; rt < 4; ++rt) {
        #pragma unroll
        for (int q = 0; q < 4; ++q)
            pb2[(size_t)(r0 + rt * 16 + rb + q) * DIM + n0 + (lane & 15)] = acc[rt][q];
    }
}

// ---------------------------------------------------------------------------
// K5: reduce split-K partials -> out (vectorized; part is L2-warm)
// ---------------------------------------------------------------------------
__global__ __launch_bounds__(256) void k5_reduce(const float* __restrict__ part,
                                                 float* __restrict__ out) {
    const size_t idx = ((size_t)blockIdx.x * 256 + threadIdx.x) * 4;
    f32x4 s = (f32x4){0.f, 0.f, 0.f, 0.f};
    #pragma unroll
    for (int ks = 0; ks < KS; ++ks)
        s += *(const f32x4*)(part + (size_t)ks * NN * DIM + idx);
    *(f32x4*)(out + idx) = s;
}

// ---------------------------------------------------------------------------
extern "C" void kernel_launch(void* const* d_in, const int* in_sizes, int n_in,
                              void* d_out, int out_size, void* d_ws, size_t ws_size,
                              hipStream_t stream) {
    const float* h   = (const float*)d_in[0];
    const int*   adj = (const int*)d_in[1];
    const float* W   = (const float*)d_in[2];
    const float* a   = (const float*)d_in[3];

    float* out   = (float*)d_out;
    float* alpha = out + (size_t)NN * DIM;

    char* ws = (char*)d_ws;
    __hip_bfloat16* whbT = (__hip_bfloat16*)(ws);          // 2 MB
    float* a1g   = (float*)(ws + 0x200000);                // 32 KB
    float2* pk   = (float2*)(ws + 0x208000);               // 64 KB
    float* crow  = (float*)(ws + 0x218000);                // 128 KB
    unsigned* bm = (unsigned*)(ws + 0x240000);             // 8 MB
    float* part  = (float*)(ws + 0xA40000);                // KS*4 MB = 32 MB

    k1m<<<NN / 64, 256, 0, stream>>>(h, W, a, whbT, a1g, pk);
    sa_scan<<<NN / 4, 256, 0, stream>>>(adj, a1g, pk, bm, crow);
    sb_pv<<<dim3(NN / RPB, KS), 512, 0, stream>>>(bm, crow, pk, whbT, alpha, part);
    k5_reduce<<<NN * DIM / 1024, 256, 0, stream>>>(part, out);
}

// Round 11
// 167.604 us; speedup vs baseline: 1.1137x; 1.0028x over previous
//
#include <hip/hip_runtime.h>
#include <hip/hip_bf16.h>

#define NN 8192
#define DIM 128
#define KS 8            // split-K factor for PV
#define KSL (NN / KS)   // 1024 k per slice
#define RPB 64          // rows per SB block
#define KC 128          // k-chunk width in SB

typedef __attribute__((ext_vector_type(8))) short bf16x8;
typedef __attribute__((ext_vector_type(4))) float f32x4;
typedef __attribute__((ext_vector_type(4))) int i32x4;
typedef __attribute__((ext_vector_type(4))) unsigned int u32x4;
typedef __attribute__((ext_vector_type(4))) unsigned short u16x4;
typedef __attribute__((ext_vector_type(4))) short s16x4;

static __device__ inline unsigned short f2bf(float x) {
    __hip_bfloat16 b = __float2bfloat16(x);
    return *reinterpret_cast<unsigned short*>(&b);
}

struct BSplit { short hi, lo; };
static __device__ inline BSplit bsplit(float x) {
    BSplit r;
    __hip_bfloat16 h = __float2bfloat16(x);
    r.hi = *reinterpret_cast<short*>(&h);
    float rem = x - __bfloat162float(h);
    __hip_bfloat16 l = __float2bfloat16(rem);
    r.lo = *reinterpret_cast<short*>(&l);
    return r;
}

// ---------------------------------------------------------------------------
// K1M: Wh = h@W^T (split-bf16 MFMA, f32-grade), a1/a2 from the f32
// accumulators, packed tables pk[i] = {a2, bf16(E1)|bf16(E2)<<16}, and
// whbT (bf16, tiled [k>>3][dim][k&7]). grid 128 x 64 rows, 4 waves.
// ---------------------------------------------------------------------------
__global__ __launch_bounds__(256) void k1m(const float* __restrict__ h,
                                           const float* __restrict__ W,
                                           const float* __restrict__ a,
                                           __hip_bfloat16* __restrict__ whbT,
                                           float* __restrict__ a1g,
                                           float2* __restrict__ pk) {
    __shared__ short whi[128 * 132];         // W hi, row stride 132 (264B)
    __shared__ short wlo[128 * 132];         // W lo
    __shared__ short wt[8 * 128 * 8];        // whbT retile staging (16 KB)
    __shared__ float a_sh[256];

    const int tid = threadIdx.x;
    const int wv = tid >> 6, lane = tid & 63;
    const int r0 = blockIdx.x * 64;

    for (int idx = tid; idx < 128 * 128; idx += 256) {
        const int d = idx >> 7, k = idx & 127;
        BSplit s = bsplit(W[idx]);
        whi[d * 132 + k] = s.hi;
        wlo[d * 132 + k] = s.lo;
    }
    a_sh[tid] = a[tid];
    __syncthreads();

    f32x4 acc[8];
    #pragma unroll
    for (int n = 0; n < 8; ++n) acc[n] = (f32x4){0.f, 0.f, 0.f, 0.f};

    const int arow = r0 + wv * 16 + (lane & 15);
    const int ksub = (lane >> 4) * 8;
    const float* hp = h + (size_t)arow * DIM + ksub;

    #pragma unroll
    for (int kk = 0; kk < 128; kk += 32) {
        f32x4 x0 = *(const f32x4*)(hp + kk);
        f32x4 x1 = *(const f32x4*)(hp + kk + 4);
        bf16x8 ah, al;
        {
            BSplit s0 = bsplit(x0.x), s1 = bsplit(x0.y), s2 = bsplit(x0.z), s3 = bsplit(x0.w);
            BSplit s4 = bsplit(x1.x), s5 = bsplit(x1.y), s6 = bsplit(x1.z), s7 = bsplit(x1.w);
            ah[0] = s0.hi; al[0] = s0.lo; ah[1] = s1.hi; al[1] = s1.lo;
            ah[2] = s2.hi; al[2] = s2.lo; ah[3] = s3.hi; al[3] = s3.lo;
            ah[4] = s4.hi; al[4] = s4.lo; ah[5] = s5.hi; al[5] = s5.lo;
            ah[6] = s6.hi; al[6] = s6.lo; ah[7] = s7.hi; al[7] = s7.lo;
        }
        #pragma unroll
        for (int n = 0; n < 8; ++n) {
            const int boff = (n * 16 + (lane & 15)) * 132 + kk + ksub;
            bf16x8 bh = *(const bf16x8*)(whi + boff);
            bf16x8 bl = *(const bf16x8*)(wlo + boff);
            acc[n] = __builtin_amdgcn_mfma_f32_16x16x32_bf16(ah, bh, acc[n], 0, 0, 0);
            acc[n] = __builtin_amdgcn_mfma_f32_16x16x32_bf16(ah, bl, acc[n], 0, 0, 0);
            acc[n] = __builtin_amdgcn_mfma_f32_16x16x32_bf16(al, bh, acc[n], 0, 0, 0);
        }
    }

    float p1[4] = {0.f, 0.f, 0.f, 0.f}, p2[4] = {0.f, 0.f, 0.f, 0.f};
    #pragma unroll
    for (int n = 0; n < 8; ++n) {
        const float av1 = a_sh[n * 16 + (lane & 15)];
        const float av2 = a_sh[128 + n * 16 + (lane & 15)];
        #pragma unroll
        for (int q = 0; q < 4; ++q) {
            p1[q] += acc[n][q] * av1;
            p2[q] += acc[n][q] * av2;
        }
    }
    #pragma unroll
    for (int o = 8; o >= 1; o >>= 1) {
        #pragma unroll
        for (int q = 0; q < 4; ++q) {
            p1[q] += __shfl_xor(p1[q], o, 64);
            p2[q] += __shfl_xor(p2[q], o, 64);
        }
    }
    if ((lane & 15) == 0) {
        #pragma unroll
        for (int q = 0; q < 4; ++q) {
            const int row = r0 + wv * 16 + (lane >> 4) * 4 + q;
            a1g[row] = p1[q];
            const float E1v = expf(p2[q]);
            const float E2v = expf(0.2f * p2[q]);
            unsigned ub = (unsigned)f2bf(E1v) | ((unsigned)f2bf(E2v) << 16);
            float2 pv;
            pv.x = p2[q];
            pv.y = __uint_as_float(ub);
            pk[row] = pv;
        }
    }

    #pragma unroll
    for (int n = 0; n < 8; ++n) {
        #pragma unroll
        for (int q = 0; q < 4; ++q) {
            const int kloc = wv * 16 + (lane >> 4) * 4 + q;   // block-local k
            const int d = n * 16 + (lane & 15);
            wt[(kloc >> 3) * 1024 + d * 8 + (kloc & 7)] = (short)f2bf(acc[n][q]);
        }
    }
    __syncthreads();
    short* dst = reinterpret_cast<short*>(whbT) + ((size_t)r0 << 7);
    for (int idx = tid * 4; idx < 8192; idx += 1024)
        *(s16x4*)(dst + idx) = *(const s16x4*)(wt + idx);
}

// ---------------------------------------------------------------------------
// SA v2: stream adj with 4x batched issue (1024-col super-iterations: 4 NT
// adj i32x4 + 8 table f32x4 loads in flight before any ballot consumes them)
// -> higher MLP, higher stream BW. Bit layout unchanged:
// col j -> word (j>>8)*8 + ((j>>7)&1)*4 + (j&3), bit (j>>2)&31.
// ---------------------------------------------------------------------------
static __device__ inline void sa_group(const i32x4 v, const f32x4 pa, const f32x4 pb,
                                       const float a1i, const int lane,
                                       float& s1, float& s2,
                                       unsigned* __restrict__ bgrp) {
    unsigned long long m0 = __ballot(v.x != 0);
    unsigned long long m1 = __ballot(v.y != 0);
    unsigned long long m2 = __ballot(v.z != 0);
    unsigned long long m3 = __ballot(v.w != 0);
    if (lane == 0) {
        u32x4 w;
        w.x = (unsigned)m0; w.y = (unsigned)m1;
        w.z = (unsigned)m2; w.w = (unsigned)m3;
        *(u32x4*)(bgrp) = w;
    } else if (lane == 32) {
        u32x4 w;
        w.x = (unsigned)(m0 >> 32); w.y = (unsigned)(m1 >> 32);
        w.z = (unsigned)(m2 >> 32); w.w = (unsigned)(m3 >> 32);
        *(u32x4*)(bgrp + 4) = w;
    }
    float x2, e1, e2; unsigned ub; bool px;
    x2 = pa.x; ub = __float_as_uint(pa.y);
    e1 = __uint_as_float(ub << 16); e2 = __uint_as_float(ub & 0xffff0000u);
    px = (a1i + x2 >= 0.f);
    s1 += (v.x && px) ? e1 : 0.f;  s2 += (v.x && !px) ? e2 : 0.f;
    x2 = pa.z; ub = __float_as_uint(pa.w);
    e1 = __uint_as_float(ub << 16); e2 = __uint_as_float(ub & 0xffff0000u);
    px = (a1i + x2 >= 0.f);
    s1 += (v.y && px) ? e1 : 0.f;  s2 += (v.y && !px) ? e2 : 0.f;
    x2 = pb.x; ub = __float_as_uint(pb.y);
    e1 = __uint_as_float(ub << 16); e2 = __uint_as_float(ub & 0xffff0000u);
    px = (a1i + x2 >= 0.f);
    s1 += (v.z && px) ? e1 : 0.f;  s2 += (v.z && !px) ? e2 : 0.f;
    x2 = pb.z; ub = __float_as_uint(pb.w);
    e1 = __uint_as_float(ub << 16); e2 = __uint_as_float(ub & 0xffff0000u);
    px = (a1i + x2 >= 0.f);
    s1 += (v.w && px) ? e1 : 0.f;  s2 += (v.w && !px) ? e2 : 0.f;
}

__global__ __launch_bounds__(256) void sa_scan(const int* __restrict__ adj,
                                               const float* __restrict__ a1g,
                                               const float2* __restrict__ pk,
                                               unsigned* __restrict__ bm,
                                               float* __restrict__ crow) {
    const int wid = threadIdx.x >> 6, lane = threadIdx.x & 63;
    const int i = blockIdx.x * 4 + wid;
    const float a1i = a1g[i];
    const int* arow = adj + (size_t)i * NN;
    unsigned* brow = bm + (size_t)i * (NN / 32);
    const float* pkf = reinterpret_cast<const float*>(pk);

    float s1 = 0.f, s2 = 0.f;
    for (int it = 0; it < NN / 1024; ++it) {
        const int j0 = it * 1024 + lane * 4;
        // batched issue: 4 adj NT loads + 8 table loads, no consumer between
        i32x4 v0 = __builtin_nontemporal_load((const i32x4*)(arow + j0));
        i32x4 v1 = __builtin_nontemporal_load((const i32x4*)(arow + j0 + 256));
        i32x4 v2 = __builtin_nontemporal_load((const i32x4*)(arow + j0 + 512));
        i32x4 v3 = __builtin_nontemporal_load((const i32x4*)(arow + j0 + 768));
        f32x4 pa0 = *(const f32x4*)(pkf + 2 * j0);
        f32x4 pb0 = *(const f32x4*)(pkf + 2 * j0 + 4);
        f32x4 pa1 = *(const f32x4*)(pkf + 2 * (j0 + 256));
        f32x4 pb1 = *(const f32x4*)(pkf + 2 * (j0 + 256) + 4);
        f32x4 pa2 = *(const f32x4*)(pkf + 2 * (j0 + 512));
        f32x4 pb2 = *(const f32x4*)(pkf + 2 * (j0 + 512) + 4);
        f32x4 pa3 = *(const f32x4*)(pkf + 2 * (j0 + 768));
        f32x4 pb3 = *(const f32x4*)(pkf + 2 * (j0 + 768) + 4);
        unsigned* bsup = brow + it * 32;      // 4 groups x 8 words
        sa_group(v0, pa0, pb0, a1i, lane, s1, s2, bsup);
        sa_group(v1, pa1, pb1, a1i, lane, s1, s2, bsup + 8);
        sa_group(v2, pa2, pb2, a1i, lane, s1, s2, bsup + 16);
        sa_group(v3, pa3, pb3, a1i, lane, s1, s2, bsup + 24);
    }
    #pragma unroll
    for (int o = 32; o >= 1; o >>= 1) {
        s1 += __shfl_xor(s1, o, 64);
        s2 += __shfl_xor(s2, o, 64);
    }
    if (lane == 0) {
        float c1 = 0.f, c2 = 0.f;
        if (s1 + s2 > 0.f) {
            float e1v = expf(a1i);
            float e2v = expf(0.2f * a1i);
            float S = e1v * s1 + e2v * s2;
            c1 = e1v / S;
            c2 = e2v / S;
        }
        crow[i * 4 + 0] = c1;
        crow[i * 4 + 1] = c2;
        crow[i * 4 + 2] = a1i;
        crow[i * 4 + 3] = 0.f;
    }
}

// ---------------------------------------------------------------------------
// SB: fused alpha-write + PV MFMA, split-K. grid (NN/64, KS=8), 512 threads.
// bm quad broadcast from L2, crow in regs, LDS = abuf only -> 4 blocks/CU at
// <=64 VGPR. part stores non-NT (k5 reads from L2 where possible).
// ---------------------------------------------------------------------------
__global__ __launch_bounds__(512, 8) void sb_pv(const unsigned* __restrict__ bm,
                                                const float* __restrict__ crowG,
                                                const float2* __restrict__ pk,
                                                const __hip_bfloat16* __restrict__ whbT,
                                                float* __restrict__ alpha,
                                                float* __restrict__ part) {
    __shared__ __hip_bfloat16 abuf[2][RPB][KC + 8];      // 34.8 KB (sole LDS)

    const int tid = threadIdx.x;
    const int wv = tid >> 6, lane = tid & 63;
    const int r0 = blockIdx.x * RPB;
    const int ks = blockIdx.y;
    const int k0 = ks * KSL;
    const float* pkf = reinterpret_cast<const float*>(pk);

    const int rloc = tid >> 5;
    float c1r[4], c2r[4], a1r[4];
    #pragma unroll
    for (int v = 0; v < 4; ++v) {
        f32x4 cw = *(const f32x4*)(crowG + (size_t)(r0 + rloc + 16 * v) * 4);
        c1r[v] = cw.x; c2r[v] = cw.y; a1r[v] = cw.z;
    }

    f32x4 acc[4];
    #pragma unroll
    for (int rt = 0; rt < 4; ++rt) acc[rt] = (f32x4){0.f, 0.f, 0.f, 0.f};
    const int n0 = wv * 16;
    const short* wb = reinterpret_cast<const short*>(whbT);
    const short* bbase = wb + (size_t)(n0 + (lane & 15)) * 8 + (size_t)(lane >> 4) * 1024;

    const int cgrp = (tid & 31) << 2;
    const unsigned pbit = tid & 31;

    for (int kc = 0; kc < KSL; kc += KC) {
        const int dbuf = (kc >> 7) & 1;
        const int jl = kc + cgrp;
        const int j = k0 + jl;
        const int wbw = ((jl >> 8) << 3) + (((jl >> 7) & 1) << 2);
        f32x4 pa = *(const f32x4*)(pkf + 2 * j);
        f32x4 pb = *(const f32x4*)(pkf + 2 * j + 4);
        #pragma unroll
        for (int v = 0; v < 4; ++v) {
            const int r = rloc + 16 * v;
            const int gr = r0 + r;
            u32x4 w4 = *(const u32x4*)(bm + (size_t)gr * (NN / 32) + ks * (KSL / 32) + wbw);
            const float c1 = c1r[v], c2 = c2r[v], a1i = a1r[v];
            f32x4 al;
            {
                unsigned ub = __float_as_uint(pa.y);
                float e1 = __uint_as_float(ub << 16), e2 = __uint_as_float(ub & 0xffff0000u);
                al.x = ((w4.x >> pbit) & 1) ? ((a1i + pa.x >= 0.f) ? c1 * e1 : c2 * e2) : 0.f;
            }
            {
                unsigned ub = __float_as_uint(pa.w);
                float e1 = __uint_as_float(ub << 16), e2 = __uint_as_float(ub & 0xffff0000u);
                al.y = ((w4.y >> pbit) & 1) ? ((a1i + pa.z >= 0.f) ? c1 * e1 : c2 * e2) : 0.f;
            }
            {
                unsigned ub = __float_as_uint(pb.y);
                float e1 = __uint_as_float(ub << 16), e2 = __uint_as_float(ub & 0xffff0000u);
                al.z = ((w4.z >> pbit) & 1) ? ((a1i + pb.x >= 0.f) ? c1 * e1 : c2 * e2) : 0.f;
            }
            {
                unsigned ub = __float_as_uint(pb.w);
                float e1 = __uint_as_float(ub << 16), e2 = __uint_as_float(ub & 0xffff0000u);
                al.w = ((w4.w >> pbit) & 1) ? ((a1i + pb.z >= 0.f) ? c1 * e1 : c2 * e2) : 0.f;
            }
            __builtin_nontemporal_store(al, (f32x4*)(alpha + (size_t)gr * NN + j));
            u16x4 ub4;
            ub4.x = f2bf(al.x); ub4.y = f2bf(al.y); ub4.z = f2bf(al.z); ub4.w = f2bf(al.w);
            *(u16x4*)(&abuf[dbuf][r][cgrp]) = ub4;
        }
        __syncthreads();
        #pragma unroll
        for (int kk = 0; kk < KC; kk += 32) {
            bf16x8 bf = *(const bf16x8*)(bbase + (size_t)((k0 + kc + kk) >> 3) * 1024);
            #pragma unroll
            for (int rt = 0; rt < 4; ++rt) {
                bf16x8 af = *(const bf16x8*)(&abuf[dbuf][rt * 16 + (lane & 15)][kk + 8 * (lane >> 4)]);
                acc[rt] = __builtin_amdgcn_mfma_f32_16x16x32_bf16(af, bf, acc[rt], 0, 0, 0);
            }
        }
    }

    float* pb2 = part + (size_t)ks * NN * DIM;
    const int rb = (lane >> 4) * 4;
    #pragma unroll
    for (int rt = 0; rt < 4; ++rt) {
        #pragma unroll
        for (int q = 0; q < 4; ++q)
            pb2[(size_t)(r0 + rt * 16 + rb + q) * DIM + n0 + (lane & 15)] = acc[rt][q];
    }
}

// ---------------------------------------------------------------------------
// K5: reduce split-K partials -> out (vectorized; part is L2-warm)
// ---------------------------------------------------------------------------
__global__ __launch_bounds__(256) void k5_reduce(const float* __restrict__ part,
                                                 float* __restrict__ out) {
    const size_t idx = ((size_t)blockIdx.x * 256 + threadIdx.x) * 4;
    f32x4 s = (f32x4){0.f, 0.f, 0.f, 0.f};
    #pragma unroll
    for (int ks = 0; ks < KS; ++ks)
        s += *(const f32x4*)(part + (size_t)ks * NN * DIM + idx);
    *(f32x4*)(out + idx) = s;
}

// ---------------------------------------------------------------------------
extern "C" void kernel_launch(void* const* d_in, const int* in_sizes, int n_in,
                              void* d_out, int out_size, void* d_ws, size_t ws_size,
                              hipStream_t stream) {
    const float* h   = (const float*)d_in[0];
    const int*   adj = (const int*)d_in[1];
    const float* W   = (const float*)d_in[2];
    const float* a   = (const float*)d_in[3];

    float* out   = (float*)d_out;
    float* alpha = out + (size_t)NN * DIM;

    char* ws = (char*)d_ws;
    __hip_bfloat16* whbT = (__hip_bfloat16*)(ws);          // 2 MB
    float* a1g   = (float*)(ws + 0x200000);                // 32 KB
    float2* pk   = (float2*)(ws + 0x208000);               // 64 KB
    float* crow  = (float*)(ws + 0x218000);                // 128 KB
    unsigned* bm = (unsigned*)(ws + 0x240000);             // 8 MB
    float* part  = (float*)(ws + 0xA40000);                // KS*4 MB = 32 MB

    k1m<<<NN / 64, 256, 0, stream>>>(h, W, a, whbT, a1g, pk);
    sa_scan<<<NN / 4, 256, 0, stream>>>(adj, a1g, pk, bm, crow);
    sb_pv<<<dim3(NN / RPB, KS), 512, 0, stream>>>(bm, crow, pk, whbT, alpha, part);
    k5_reduce<<<NN * DIM / 1024, 256, 0, stream>>>(part, out);
}